// Round 6
// baseline (137.214 us; speedup 1.0000x reference)
//
#include <hip/hip_runtime.h>
#include <hip/hip_bf16.h>
#include <math.h>

typedef unsigned int u32;
typedef unsigned short u16;
typedef __bf16 bf16_t;
typedef bf16_t bf16x8 __attribute__((ext_vector_type(8)));
typedef float f32x4 __attribute__((ext_vector_type(4)));

#define B_N 8192
#define D_K 256
#define NCLS 360
#define BM 128
#define BN 64
#define BKH 128               // K half staged per u-step
#define NSPLIT 16
#define COLS (B_N / NSPLIT)   // 512
#define NT (COLS / BN)        // 8 col-tiles -> 16 u-steps
#define MAXC 61               // max class rows kept (Poisson(22.8); P(>=61) ~ 1e-12)

#define SCALE2 (-20.609929155556627f)   // -(1/0.07)*log2(e)
#define LN2 (0.6931471805599453f)
#define INV_T (14.285714285714286f)     // 1/0.07

__device__ __forceinline__ float fexp2(float x) { return __builtin_amdgcn_exp2f(x); }

__device__ __forceinline__ u16 f2bf(float x) {
  u32 u = __float_as_uint(x);
  u32 r = (u + 0x7fffu + ((u >> 16) & 1u)) >> 16;
  return (u16)r;
}

__device__ __forceinline__ void gl_lds16(const void* g, void* l) {
  __builtin_amdgcn_global_load_lds(
      (const __attribute__((address_space(1))) u32*)g,
      (__attribute__((address_space(3))) u32*)l, 16, 0, 0);
}

// ---------------- K1: convert f32 -> bf16; zero the output accumulator
__global__ void k_prep(const float* __restrict__ f, u16* __restrict__ fbf,
                       float* __restrict__ out) {
  if (blockIdx.x == 0 && threadIdx.x == 0) out[0] = 0.f;
  int t = blockIdx.x * 256 + threadIdx.x;
  int e4 = t * 4;
  const float4 v = *reinterpret_cast<const float4*>(f + e4);
  ushort4 b;
  b.x = f2bf(v.x); b.y = f2bf(v.y); b.z = f2bf(v.z); b.w = f2bf(v.w);
  *reinterpret_cast<ushort4*>(fbf + e4) = b;
}

// ---------------- K2: fused pairwise-dot + online log-sum-exp
// 2x16KB LDS halves, 4 blocks/CU, grid = 1024 = exactly 4 per CU (no tail)
__device__ __forceinline__ void stage_half(const u16* __restrict__ fb, int col0,
                                           int koff, u16* buf, int w, int lane) {
#pragma unroll
  for (int it = 0; it < 4; ++it) {
    int lin = (w * 4 + it) * 1024 + lane * 16;  // byte offset in 16KB buffer
    int row = lin >> 8;                          // 256B per row
    int c = (lin >> 4) & 15;                     // 16B chunk within row
    int sc = c ^ (row & 7);                      // pre-swizzled source chunk
    const u16* src = fb + (size_t)(col0 + row) * D_K + koff + sc * 8;
    u16* dst = buf + (w * 4 + it) * 512;         // wave-uniform base (u16 elems)
    gl_lds16(src, dst);
  }
}

__global__ __launch_bounds__(256, 4) void k_main(const u16* __restrict__ fb,
                                                 float2* __restrict__ part) {
  __shared__ __align__(16) u16 Bs[2][BN * BKH];  // 2 x 16KB

  const int tid = threadIdx.x;
  const int lane = tid & 63;
  const int w = tid >> 6;
  const int t15 = lane & 15;
  const int g = lane >> 4;
  const int t7 = t15 & 7;
  const int rb = blockIdx.x & 63;
  const int sp = blockIdx.x >> 6;
  const int rowbase = rb * BM + w * 32;
  const int colbase = sp * COLS;

  // A fragments: 32 rows x 256 K, register resident
  bf16x8 A[2][8];
#pragma unroll
  for (int rs = 0; rs < 2; ++rs)
#pragma unroll
    for (int kk = 0; kk < 8; ++kk) {
      const u16* p = fb + (size_t)(rowbase + rs * 16 + t15) * D_K + kk * 32 + g * 8;
      A[rs][kk] = *reinterpret_cast<const bf16x8*>(p);
    }

  float m2[8], Ea[8];
#pragma unroll
  for (int i = 0; i < 8; ++i) { m2[i] = -1e30f; Ea[i] = 0.f; }

  stage_half(fb, colbase, 0, &Bs[0][0], w, lane);
  __syncthreads();

  f32x4 C[2][4];
  for (int u = 0; u < 2 * NT; ++u) {
    const int h = u & 1;
    if (u + 1 < 2 * NT)
      stage_half(fb, colbase + ((u + 1) >> 1) * BN, ((u + 1) & 1) * BKH,
                 &Bs[(u + 1) & 1][0], w, lane);

    const u16* bufp = &Bs[u & 1][0];
    if (h == 0) {
      const f32x4 z4 = {0.f, 0.f, 0.f, 0.f};
#pragma unroll
      for (int rs = 0; rs < 2; ++rs)
#pragma unroll
        for (int s = 0; s < 4; ++s) C[rs][s] = z4;
    }

#pragma unroll
    for (int kp = 0; kp < 4; ++kp) {
      bf16x8 Bf[4];
#pragma unroll
      for (int s = 0; s < 4; ++s) {
        int rowB = s * 16 + t15;
        int q = (kp * 4 + g) ^ t7;               // chunk within 16-chunk row
        Bf[s] = *reinterpret_cast<const bf16x8*>(bufp + rowB * BKH + q * 8);
      }
#pragma unroll
      for (int rs = 0; rs < 2; ++rs)
#pragma unroll
        for (int s = 0; s < 4; ++s)
          C[rs][s] = __builtin_amdgcn_mfma_f32_16x16x32_bf16(A[rs][h * 4 + kp], Bf[s],
                                                             C[rs][s], 0, 0, 0);
    }

    if (h == 1) {
      // slim epilogue: online max / exp-sum only (positives exact in K3)
#pragma unroll
      for (int rs = 0; rs < 2; ++rs) {
#pragma unroll
        for (int q = 0; q < 4; ++q) {
          const int slot = rs * 4 + q;
          float c0 = C[rs][0][q], c1 = C[rs][1][q];
          float c2 = C[rs][2][q], c3 = C[rs][3][q];
          float tm = fminf(fminf(c0, c1), fminf(c2, c3));  // min dot = max logit
          float nm = fmaxf(m2[slot], tm * SCALE2);
          float sc = fexp2(m2[slot] - nm);
          float e0 = fexp2(fmaf(c0, SCALE2, -nm));
          float e1 = fexp2(fmaf(c1, SCALE2, -nm));
          float e2 = fexp2(fmaf(c2, SCALE2, -nm));
          float e3 = fexp2(fmaf(c3, SCALE2, -nm));
          Ea[slot] = fmaf(Ea[slot], sc, (e0 + e1) + (e2 + e3));
          m2[slot] = nm;
        }
      }
    }
    __syncthreads();
  }

  // cross-lane merge across the 16 column-subset lanes
#pragma unroll
  for (int st = 1; st < 16; st <<= 1) {
#pragma unroll
    for (int i = 0; i < 8; ++i) {
      float om = __shfl_xor(m2[i], st);
      float oa = __shfl_xor(Ea[i], st);
      float nm = fmaxf(m2[i], om);
      Ea[i] = Ea[i] * fexp2(m2[i] - nm) + oa * fexp2(om - nm);
      m2[i] = nm;
    }
  }
  if (t15 == 0) {
#pragma unroll
    for (int rs = 0; rs < 2; ++rs)
#pragma unroll
      for (int q = 0; q < 4; ++q) {
        int row = rowbase + rs * 16 + g * 4 + q;
        part[sp * B_N + row] = make_float2(m2[rs * 4 + q], Ea[rs * 4 + q]);
      }
  }
}

// ---------------- K3: per-class exact fp32 Gram -> Ep, sum positive dots, loss
__global__ __launch_bounds__(256) void k_final(const float* __restrict__ f,
                                               const int* __restrict__ lab,
                                               const float2* __restrict__ part,
                                               float* __restrict__ out) {
  __shared__ __align__(16) float4 feat[MAXC][65];  // 61*1040B = 63,440 B, padded
  __shared__ float m2a[MAXC], Eaa[MAXC], Epa[MAXC], sda[MAXC];
  __shared__ int idx[MAXC];
  __shared__ int nS;
  const int c = blockIdx.x;
  const int tid = threadIdx.x;
  const int lane = tid & 63;
  const int w = tid >> 6;
  if (tid == 0) nS = 0;
  __syncthreads();

  // find this class's rows (order irrelevant)
  for (int i = tid; i < B_N / 4; i += 256) {
    const int4 lv = reinterpret_cast<const int4*>(lab)[i];
    if (lv.x == c) { int p = atomicAdd(&nS, 1); if (p < MAXC) idx[p] = i * 4 + 0; }
    if (lv.y == c) { int p = atomicAdd(&nS, 1); if (p < MAXC) idx[p] = i * 4 + 1; }
    if (lv.z == c) { int p = atomicAdd(&nS, 1); if (p < MAXC) idx[p] = i * 4 + 2; }
    if (lv.w == c) { int p = atomicAdd(&nS, 1); if (p < MAXC) idx[p] = i * 4 + 3; }
  }
  __syncthreads();
  const int n = nS < MAXC ? nS : MAXC;

  // load class rows into LDS (fp32, coalesced 1KB per row)
  for (int j = w; j < n; j += 4)
    feat[j][lane] = reinterpret_cast<const float4*>(f + (size_t)idx[j] * D_K)[lane];

  // merge the NSPLIT partials per row (lanes 0..15 hold one split each)
  for (int j = w; j < n; j += 4) {
    float m2 = -1e30f, Ea = 0.f;
    if (lane < NSPLIT) {
      float2 p = part[lane * B_N + idx[j]];
      m2 = p.x; Ea = p.y;
    }
#pragma unroll
    for (int st = 1; st < NSPLIT; st <<= 1) {
      float om = __shfl_xor(m2, st);
      float oa = __shfl_xor(Ea, st);
      float nm = fmaxf(m2, om);
      Ea = Ea * fexp2(m2 - nm) + oa * fexp2(om - nm);
      m2 = nm;
    }
    if (lane == 0) { m2a[j] = m2; Eaa[j] = Ea; Epa[j] = 0.f; sda[j] = 0.f; }
  }
  __syncthreads();

  // Gram tiles: 8x8 pairs per wave-tile, one pair per lane
  const int ntile = (n + 7) >> 3;
  const int jj = lane >> 3, kk = lane & 7;
  for (int tile = w; tile < ntile * ntile; tile += 4) {
    const int j = (tile / ntile) * 8 + jj;
    const int k = (tile % ntile) * 8 + kk;
    const bool ok = (j < n) && (k < n) && (j != k);
    const int jc = j < n ? j : 0, kc = k < n ? k : 0;
    f32x4 acc = {0.f, 0.f, 0.f, 0.f};
#pragma unroll 8
    for (int d = 0; d < 64; ++d) {
      const float4 a = feat[jc][d];
      const float4 b = feat[kc][d];
      acc[0] = fmaf(a.x, b.x, acc[0]);
      acc[1] = fmaf(a.y, b.y, acc[1]);
      acc[2] = fmaf(a.z, b.z, acc[2]);
      acc[3] = fmaf(a.w, b.w, acc[3]);
    }
    float dot = ok ? ((acc[0] + acc[1]) + (acc[2] + acc[3])) : 0.f;
    float ex = ok ? fexp2(fmaf(dot, SCALE2, -m2a[jc])) : 0.f;
#pragma unroll
    for (int st = 1; st < 8; st <<= 1) {
      dot += __shfl_xor(dot, st);
      ex += __shfl_xor(ex, st);
    }
    if (kk == 0 && j < n) {
      atomicAdd(&sda[j], dot);
      atomicAdd(&Epa[j], ex);
    }
  }
  __syncthreads();

  // finalize rows of this class, reduce, one atomic per block
  if (w == 0) {
    float contrib = 0.f;
    if (lane < n) {
      const int j = lane;
      float m2 = m2a[j], Ea = Eaa[j], Ep = Epa[j], sumdot = sda[j];
      float En = fmaxf(Ea - Ep, 0.f);         // self term underflows (exp2(-5000))
      int cntp = n - 1;
      float cntn = (float)(B_N - 1 - cntp);
      float denom = Ep + En / (cntn + 1e-8f);
      float Sadc = -sumdot * INV_T;           // exact fp32 sum of positive logits
      float num = Sadc - (float)cntp * (m2 * LN2) - (float)cntp * logf(denom);
      float dv = (cntp <= 0) ? 1.f : (float)cntp;
      contrib = num / dv;
    }
#pragma unroll
    for (int st = 1; st < 64; st <<= 1) contrib += __shfl_xor(contrib, st);
    if (lane == 0) atomicAdd(out, contrib * (1.f / (float)B_N));
  }
}

extern "C" void kernel_launch(void* const* d_in, const int* in_sizes, int n_in,
                              void* d_out, int out_size, void* d_ws, size_t ws_size,
                              hipStream_t stream) {
  const float* f = (const float*)d_in[0];
  const int* lab = (const int*)d_in[1];

  char* ws = (char*)d_ws;
  u16* fbf = (u16*)ws;                        // 4 MB
  float2* part = (float2*)(ws + 4194304);     // 16*8192*8 = 1 MB

  k_prep<<<2048, 256, 0, stream>>>(f, fbf, (float*)d_out);
  k_main<<<64 * NSPLIT, 256, 0, stream>>>(fbf, part);
  k_final<<<NCLS, 256, 0, stream>>>(f, lab, part, (float*)d_out);
}

// Round 7
// 105.923 us; speedup vs baseline: 1.2954x; 1.2954x over previous
//
#include <hip/hip_runtime.h>
#include <hip/hip_bf16.h>
#include <math.h>

typedef unsigned int u32;
typedef unsigned short u16;
typedef __bf16 bf16_t;
typedef bf16_t bf16x8 __attribute__((ext_vector_type(8)));
typedef float f32x4 __attribute__((ext_vector_type(4)));

#define B_N 8192
#define D_K 256
#define NCLS 360
#define BM 256                // 4 waves x 64 rows -> halves LDS-read per output
#define BN 64
#define NSPLIT 16
#define COLS (B_N / NSPLIT)   // 512
#define NT (COLS / BN)        // 8 col-tiles per block
#define MAXC 61               // max class rows kept (Poisson(22.8); P(>=61) ~ 1e-12)

#define SCALE2 (-20.609929155556627f)   // -(1/0.07)*log2(e)
#define LN2 (0.6931471805599453f)
#define INV_T (14.285714285714286f)     // 1/0.07

__device__ __forceinline__ float fexp2(float x) { return __builtin_amdgcn_exp2f(x); }

__device__ __forceinline__ u16 f2bf(float x) {
  u32 u = __float_as_uint(x);
  u32 r = (u + 0x7fffu + ((u >> 16) & 1u)) >> 16;
  return (u16)r;
}

__device__ __forceinline__ void gl_lds16(const void* g, void* l) {
  __builtin_amdgcn_global_load_lds(
      (const __attribute__((address_space(1))) u32*)g,
      (__attribute__((address_space(3))) u32*)l, 16, 0, 0);
}

// ---------------- K1: convert f32 -> bf16; zero the output accumulator
__global__ void k_prep(const float* __restrict__ f, u16* __restrict__ fbf,
                       float* __restrict__ out) {
  if (blockIdx.x == 0 && threadIdx.x == 0) out[0] = 0.f;
  int t = blockIdx.x * 256 + threadIdx.x;
  int e4 = t * 4;
  const float4 v = *reinterpret_cast<const float4*>(f + e4);
  ushort4 b;
  b.x = f2bf(v.x); b.y = f2bf(v.y); b.z = f2bf(v.z); b.w = f2bf(v.w);
  *reinterpret_cast<ushort4*>(fbf + e4) = b;
}

// ---------------- K2: fused pairwise-dot + online log-sum-exp
// BM=256: each wave owns 64 rows, reads the shared 64x256 B-tile once ->
// LDS-read traffic halves vs 32-row waves. 2x32KB dbuf, 2 blocks/CU exact.
__device__ __forceinline__ void stage_tile(const u16* __restrict__ fb, int col0,
                                           u16* buf, int w, int lane) {
#pragma unroll
  for (int it = 0; it < 8; ++it) {
    int lin = (w * 8 + it) * 1024 + lane * 16;  // byte offset in 32KB tile
    int row = lin >> 9;                          // 512B per row
    int c = (lin >> 4) & 31;                     // 16B chunk in row
    int q = c ^ (row & 7);                       // pre-swizzled source chunk
    const u16* src = fb + (size_t)(col0 + row) * D_K + q * 8;
    u16* dst = buf + (w * 8 + it) * 512;         // wave-uniform base (u16 elems)
    gl_lds16(src, dst);
  }
}

__global__ __launch_bounds__(256, 2) void k_main(const u16* __restrict__ fb,
                                                 float2* __restrict__ part) {
  __shared__ __align__(16) u16 Bs[2][BN * D_K];  // 2 x 32KB

  const int tid = threadIdx.x;
  const int lane = tid & 63;
  const int w = tid >> 6;
  const int t15 = lane & 15;
  const int g = lane >> 4;
  const int t7 = t15 & 7;
  const int rb = blockIdx.x & 31;   // 32 row-blocks of 256 rows
  const int sp = blockIdx.x >> 5;   // 16 col-splits
  const int rowbase = rb * BM + w * 64;
  const int colbase = sp * COLS;

  // A fragments: 64 rows x 256 K, register resident (32 x 16B = 128 VGPR)
  bf16x8 A[4][8];
#pragma unroll
  for (int rs = 0; rs < 4; ++rs)
#pragma unroll
    for (int kk = 0; kk < 8; ++kk) {
      const u16* p = fb + (size_t)(rowbase + rs * 16 + t15) * D_K + kk * 32 + g * 8;
      A[rs][kk] = *reinterpret_cast<const bf16x8*>(p);
    }

  float m2[16], Ea[16];
#pragma unroll
  for (int i = 0; i < 16; ++i) { m2[i] = -1e30f; Ea[i] = 0.f; }

  stage_tile(fb, colbase, &Bs[0][0], w, lane);
  __syncthreads();

  for (int t = 0; t < NT; ++t) {
    if (t + 1 < NT) stage_tile(fb, colbase + (t + 1) * BN, &Bs[(t + 1) & 1][0], w, lane);

    const u16* bufp = &Bs[t & 1][0];
    f32x4 C[4][4];
    const f32x4 z4 = {0.f, 0.f, 0.f, 0.f};
#pragma unroll
    for (int rs = 0; rs < 4; ++rs)
#pragma unroll
      for (int s = 0; s < 4; ++s) C[rs][s] = z4;

#pragma unroll
    for (int kk = 0; kk < 8; ++kk) {
      bf16x8 Bf[4];
#pragma unroll
      for (int s = 0; s < 4; ++s) {
        int rowB = s * 16 + t15;
        int q = (kk * 4 + g) ^ t7;
        Bf[s] = *reinterpret_cast<const bf16x8*>(bufp + rowB * D_K + q * 8);
      }
#pragma unroll
      for (int rs = 0; rs < 4; ++rs)
#pragma unroll
        for (int s = 0; s < 4; ++s)
          C[rs][s] = __builtin_amdgcn_mfma_f32_16x16x32_bf16(A[rs][kk], Bf[s],
                                                             C[rs][s], 0, 0, 0);
    }

    // slim epilogue: online max / exp-sum only (positives exact in K3)
#pragma unroll
    for (int rs = 0; rs < 4; ++rs) {
#pragma unroll
      for (int q = 0; q < 4; ++q) {
        const int slot = rs * 4 + q;
        float c0 = C[rs][0][q], c1 = C[rs][1][q];
        float c2 = C[rs][2][q], c3 = C[rs][3][q];
        float tm = fminf(fminf(c0, c1), fminf(c2, c3));  // min dot = max logit
        float nm = fmaxf(m2[slot], tm * SCALE2);
        float sc = fexp2(m2[slot] - nm);
        float e0 = fexp2(fmaf(c0, SCALE2, -nm));
        float e1 = fexp2(fmaf(c1, SCALE2, -nm));
        float e2 = fexp2(fmaf(c2, SCALE2, -nm));
        float e3 = fexp2(fmaf(c3, SCALE2, -nm));
        Ea[slot] = fmaf(Ea[slot], sc, (e0 + e1) + (e2 + e3));
        m2[slot] = nm;
      }
    }
    __syncthreads();
  }

  // cross-lane merge across the 16 column-subset lanes
#pragma unroll
  for (int st = 1; st < 16; st <<= 1) {
#pragma unroll
    for (int i = 0; i < 16; ++i) {
      float om = __shfl_xor(m2[i], st);
      float oa = __shfl_xor(Ea[i], st);
      float nm = fmaxf(m2[i], om);
      Ea[i] = Ea[i] * fexp2(m2[i] - nm) + oa * fexp2(om - nm);
      m2[i] = nm;
    }
  }
  if (t15 == 0) {
#pragma unroll
    for (int rs = 0; rs < 4; ++rs)
#pragma unroll
      for (int q = 0; q < 4; ++q) {
        int row = rowbase + rs * 16 + g * 4 + q;
        part[sp * B_N + row] = make_float2(m2[rs * 4 + q], Ea[rs * 4 + q]);
      }
  }
}

// ---------------- K3: per-class exact fp32 Gram -> Ep, sum positive dots, loss
__global__ __launch_bounds__(256) void k_final(const float* __restrict__ f,
                                               const int* __restrict__ lab,
                                               const float2* __restrict__ part,
                                               float* __restrict__ out) {
  __shared__ __align__(16) float4 feat[MAXC][65];  // 61*1040B = 63,440 B, padded
  __shared__ float m2a[MAXC], Eaa[MAXC], Epa[MAXC], sda[MAXC];
  __shared__ int idx[MAXC];
  __shared__ int nS;
  const int c = blockIdx.x;
  const int tid = threadIdx.x;
  const int lane = tid & 63;
  const int w = tid >> 6;
  if (tid == 0) nS = 0;
  __syncthreads();

  // find this class's rows (order irrelevant)
  for (int i = tid; i < B_N / 4; i += 256) {
    const int4 lv = reinterpret_cast<const int4*>(lab)[i];
    if (lv.x == c) { int p = atomicAdd(&nS, 1); if (p < MAXC) idx[p] = i * 4 + 0; }
    if (lv.y == c) { int p = atomicAdd(&nS, 1); if (p < MAXC) idx[p] = i * 4 + 1; }
    if (lv.z == c) { int p = atomicAdd(&nS, 1); if (p < MAXC) idx[p] = i * 4 + 2; }
    if (lv.w == c) { int p = atomicAdd(&nS, 1); if (p < MAXC) idx[p] = i * 4 + 3; }
  }
  __syncthreads();
  const int n = nS < MAXC ? nS : MAXC;

  // load class rows into LDS (fp32, coalesced 1KB per row)
  for (int j = w; j < n; j += 4)
    feat[j][lane] = reinterpret_cast<const float4*>(f + (size_t)idx[j] * D_K)[lane];

  // merge the NSPLIT partials per row (lanes 0..15 hold one split each)
  for (int j = w; j < n; j += 4) {
    float m2 = -1e30f, Ea = 0.f;
    if (lane < NSPLIT) {
      float2 p = part[lane * B_N + idx[j]];
      m2 = p.x; Ea = p.y;
    }
#pragma unroll
    for (int st = 1; st < NSPLIT; st <<= 1) {
      float om = __shfl_xor(m2, st);
      float oa = __shfl_xor(Ea, st);
      float nm = fmaxf(m2, om);
      Ea = Ea * fexp2(m2 - nm) + oa * fexp2(om - nm);
      m2 = nm;
    }
    if (lane == 0) { m2a[j] = m2; Eaa[j] = Ea; Epa[j] = 0.f; sda[j] = 0.f; }
  }
  __syncthreads();

  // Gram tiles: 8x8 pairs per wave-tile, one pair per lane
  const int ntile = (n + 7) >> 3;
  const int jj = lane >> 3, kk = lane & 7;
  for (int tile = w; tile < ntile * ntile; tile += 4) {
    const int j = (tile / ntile) * 8 + jj;
    const int k = (tile % ntile) * 8 + kk;
    const bool ok = (j < n) && (k < n) && (j != k);
    const int jc = j < n ? j : 0, kc = k < n ? k : 0;
    f32x4 acc = {0.f, 0.f, 0.f, 0.f};
#pragma unroll 8
    for (int d = 0; d < 64; ++d) {
      const float4 a = feat[jc][d];
      const float4 b = feat[kc][d];
      acc[0] = fmaf(a.x, b.x, acc[0]);
      acc[1] = fmaf(a.y, b.y, acc[1]);
      acc[2] = fmaf(a.z, b.z, acc[2]);
      acc[3] = fmaf(a.w, b.w, acc[3]);
    }
    float dot = ok ? ((acc[0] + acc[1]) + (acc[2] + acc[3])) : 0.f;
    float ex = ok ? fexp2(fmaf(dot, SCALE2, -m2a[jc])) : 0.f;
#pragma unroll
    for (int st = 1; st < 8; st <<= 1) {
      dot += __shfl_xor(dot, st);
      ex += __shfl_xor(ex, st);
    }
    if (kk == 0 && j < n) {
      atomicAdd(&sda[j], dot);
      atomicAdd(&Epa[j], ex);
    }
  }
  __syncthreads();

  // finalize rows of this class, reduce, one atomic per block
  if (w == 0) {
    float contrib = 0.f;
    if (lane < n) {
      const int j = lane;
      float m2 = m2a[j], Ea = Eaa[j], Ep = Epa[j], sumdot = sda[j];
      float En = fmaxf(Ea - Ep, 0.f);         // self term underflows (exp2(-5000))
      int cntp = n - 1;
      float cntn = (float)(B_N - 1 - cntp);
      float denom = Ep + En / (cntn + 1e-8f);
      float Sadc = -sumdot * INV_T;           // exact fp32 sum of positive logits
      float num = Sadc - (float)cntp * (m2 * LN2) - (float)cntp * logf(denom);
      float dv = (cntp <= 0) ? 1.f : (float)cntp;
      contrib = num / dv;
    }
#pragma unroll
    for (int st = 1; st < 64; st <<= 1) contrib += __shfl_xor(contrib, st);
    if (lane == 0) atomicAdd(out, contrib * (1.f / (float)B_N));
  }
}

extern "C" void kernel_launch(void* const* d_in, const int* in_sizes, int n_in,
                              void* d_out, int out_size, void* d_ws, size_t ws_size,
                              hipStream_t stream) {
  const float* f = (const float*)d_in[0];
  const int* lab = (const int*)d_in[1];

  char* ws = (char*)d_ws;
  u16* fbf = (u16*)ws;                        // 4 MB
  float2* part = (float2*)(ws + 4194304);     // 16*8192*8 = 1 MB

  k_prep<<<2048, 256, 0, stream>>>(f, fbf, (float*)d_out);
  k_main<<<32 * NSPLIT, 256, 0, stream>>>(fbf, part);
  k_final<<<NCLS, 256, 0, stream>>>(f, lab, part, (float*)d_out);
}

// Round 8
// 69.468 us; speedup vs baseline: 1.9752x; 1.5248x over previous
//
#include <hip/hip_runtime.h>
#include <hip/hip_bf16.h>
#include <math.h>

typedef unsigned int u32;
typedef unsigned short u16;
typedef __bf16 bf16_t;
typedef bf16_t bf16x8 __attribute__((ext_vector_type(8)));
typedef float f32x4 __attribute__((ext_vector_type(4)));

#define B_N 8192
#define D_K 256
#define NCLS 360
#define BM 128
#define BN 64
#define NSPLIT 8
#define COLS (B_N / NSPLIT)   // 1024
#define NT (COLS / BN)        // 16
#define MAXC 61               // max class rows kept (Poisson(22.8); P(>=61) ~ 1e-12)

#define SCALE2 (-20.609929155556627f)   // -(1/0.07)*log2(e)
#define LN2 (0.6931471805599453f)
#define INV_T (14.285714285714286f)     // 1/0.07

__device__ __forceinline__ float fexp2(float x) { return __builtin_amdgcn_exp2f(x); }

__device__ __forceinline__ u16 f2bf(float x) {
  u32 u = __float_as_uint(x);
  u32 r = (u + 0x7fffu + ((u >> 16) & 1u)) >> 16;
  return (u16)r;
}

__device__ __forceinline__ void gl_lds16(const void* g, void* l) {
  __builtin_amdgcn_global_load_lds(
      (const __attribute__((address_space(1))) u32*)g,
      (__attribute__((address_space(3))) u32*)l, 16, 0, 0);
}

// ---------------- K1: convert f32 -> bf16; zero the output accumulator
__global__ void k_prep(const float* __restrict__ f, u16* __restrict__ fbf,
                       float* __restrict__ out) {
  if (blockIdx.x == 0 && threadIdx.x == 0) out[0] = 0.f;
  int t = blockIdx.x * 256 + threadIdx.x;
  int e4 = t * 4;
  const float4 v = *reinterpret_cast<const float4*>(f + e4);
  ushort4 b;
  b.x = f2bf(v.x); b.y = f2bf(v.y); b.z = f2bf(v.z); b.w = f2bf(v.w);
  *reinterpret_cast<ushort4*>(fbf + e4) = b;
}

// ---------------- K2: fused pairwise-dot + online log-sum-exp
// Round-5 structure (proven 48 us) + addressing micro-opts:
//  - all ds_read addresses = 2 per-lane bases + compile-time immediates
//  - stage src/dst pointers hoisted out of the loop (stride add per tile)
//  - C initialized by kk=0 MFMA with a shared zero operand (no v_mov block)
__global__ __launch_bounds__(256, 2) void k_main(const u16* __restrict__ fb,
                                                 float2* __restrict__ part) {
  __shared__ __align__(16) u16 Bs[2][BN * D_K];  // 2 x 32KB

  const int tid = threadIdx.x;
  const int lane = tid & 63;
  const int w = tid >> 6;
  const int t15 = lane & 15;
  const int g = lane >> 4;
  const int t7 = t15 & 7;
  const int rb = blockIdx.x & 63;
  const int sp = blockIdx.x >> 6;
  const int rowbase = rb * BM + w * 32;
  const int colbase = sp * COLS;

  // A fragments: 32 rows x 256 K, register resident
  bf16x8 A[2][8];
#pragma unroll
  for (int rs = 0; rs < 2; ++rs)
#pragma unroll
    for (int kk = 0; kk < 8; ++kk) {
      const u16* p = fb + (size_t)(rowbase + rs * 16 + t15) * D_K + kk * 32 + g * 8;
      A[rs][kk] = *reinterpret_cast<const bf16x8*>(p);
    }

  // hoisted staging pointers: src row/chunk pattern is tile-invariant
  const u16* srcp[8];
  u16* dstp[8];
#pragma unroll
  for (int it = 0; it < 8; ++it) {
    int lin = (w * 8 + it) * 1024 + lane * 16;  // byte offset in 32KB tile
    int row = lin >> 9;                          // 512B per row
    int c = (lin >> 4) & 31;                     // 16B chunk in row
    int q = c ^ (row & 7);                       // pre-swizzled source chunk
    srcp[it] = fb + (size_t)(colbase + row) * D_K + q * 8;
    dstp[it] = &Bs[0][0] + (w * 8 + it) * 512;
  }

  // ds_read base decomposition:
  // chunk q(kk) = ((kk<<2)|g)^t7 -> bits: [kk>>1 | (kk&1)^b2 | g^(t7&3)]
  const int gl = g ^ (t7 & 3);
  const int b2 = (t7 >> 2) & 1;
  const int offE = t15 * 256 + b2 * 32 + gl * 8;        // kk even
  const int offO = t15 * 256 + (b2 ^ 1) * 32 + gl * 8;  // kk odd

  float m2[8], Ea[8];
#pragma unroll
  for (int i = 0; i < 8; ++i) { m2[i] = -1e30f; Ea[i] = 0.f; }

#pragma unroll
  for (int it = 0; it < 8; ++it) gl_lds16(srcp[it], dstp[it]);
  __syncthreads();

  const f32x4 z4 = {0.f, 0.f, 0.f, 0.f};
  for (int t = 0; t < NT; ++t) {
    if (t + 1 < NT) {
      const int soff = (t + 1) * (BN * D_K);     // 16384 elements per tile
      const int doff = ((t + 1) & 1) * (BN * D_K / 4);  // 16384 u16 = 32KB
#pragma unroll
      for (int it = 0; it < 8; ++it) gl_lds16(srcp[it] + soff, dstp[it] + doff * 4);
    }

    const u16* bufp = &Bs[t & 1][0];
    const u16* beE = bufp + offE;
    const u16* beO = bufp + offO;

    f32x4 C[2][4];
#pragma unroll
    for (int kk = 0; kk < 8; ++kk) {
      bf16x8 Bf[4];
#pragma unroll
      for (int s = 0; s < 4; ++s) {
        const u16* ba = (kk & 1) ? beO : beE;
        Bf[s] = *reinterpret_cast<const bf16x8*>(ba + (kk >> 1) * 64 + s * 4096);
      }
#pragma unroll
      for (int rs = 0; rs < 2; ++rs)
#pragma unroll
        for (int s = 0; s < 4; ++s)
          C[rs][s] = __builtin_amdgcn_mfma_f32_16x16x32_bf16(
              A[rs][kk], Bf[s], (kk == 0) ? z4 : C[rs][s], 0, 0, 0);
    }

    // slim epilogue: online max / exp-sum only (positives exact in K3)
#pragma unroll
    for (int rs = 0; rs < 2; ++rs) {
#pragma unroll
      for (int q = 0; q < 4; ++q) {
        const int slot = rs * 4 + q;
        float c0 = C[rs][0][q], c1 = C[rs][1][q];
        float c2 = C[rs][2][q], c3 = C[rs][3][q];
        float tm = fminf(fminf(c0, c1), fminf(c2, c3));  // min dot = max logit
        float nm = fmaxf(m2[slot], tm * SCALE2);
        float sc = fexp2(m2[slot] - nm);
        float e0 = fexp2(fmaf(c0, SCALE2, -nm));
        float e1 = fexp2(fmaf(c1, SCALE2, -nm));
        float e2 = fexp2(fmaf(c2, SCALE2, -nm));
        float e3 = fexp2(fmaf(c3, SCALE2, -nm));
        Ea[slot] = fmaf(Ea[slot], sc, (e0 + e1) + (e2 + e3));
        m2[slot] = nm;
      }
    }
    __syncthreads();
  }

  // cross-lane merge across the 16 column-subset lanes
#pragma unroll
  for (int st = 1; st < 16; st <<= 1) {
#pragma unroll
    for (int i = 0; i < 8; ++i) {
      float om = __shfl_xor(m2[i], st);
      float oa = __shfl_xor(Ea[i], st);
      float nm = fmaxf(m2[i], om);
      Ea[i] = Ea[i] * fexp2(m2[i] - nm) + oa * fexp2(om - nm);
      m2[i] = nm;
    }
  }
  if (t15 == 0) {
#pragma unroll
    for (int rs = 0; rs < 2; ++rs)
#pragma unroll
      for (int q = 0; q < 4; ++q) {
        int row = rowbase + rs * 16 + g * 4 + q;
        part[sp * B_N + row] = make_float2(m2[rs * 4 + q], Ea[rs * 4 + q]);
      }
  }
}

// ---------------- K3: per-class exact fp32 Gram -> Ep, sum positive dots, loss
__global__ __launch_bounds__(256) void k_final(const float* __restrict__ f,
                                               const int* __restrict__ lab,
                                               const float2* __restrict__ part,
                                               float* __restrict__ out) {
  __shared__ __align__(16) float4 feat[MAXC][65];  // 61*1040B = 63,440 B, padded
  __shared__ float m2a[MAXC], Eaa[MAXC], Epa[MAXC], sda[MAXC];
  __shared__ int idx[MAXC];
  __shared__ int nS;
  const int c = blockIdx.x;
  const int tid = threadIdx.x;
  const int lane = tid & 63;
  const int w = tid >> 6;
  if (tid == 0) nS = 0;
  __syncthreads();

  // find this class's rows (order irrelevant)
  for (int i = tid; i < B_N / 4; i += 256) {
    const int4 lv = reinterpret_cast<const int4*>(lab)[i];
    if (lv.x == c) { int p = atomicAdd(&nS, 1); if (p < MAXC) idx[p] = i * 4 + 0; }
    if (lv.y == c) { int p = atomicAdd(&nS, 1); if (p < MAXC) idx[p] = i * 4 + 1; }
    if (lv.z == c) { int p = atomicAdd(&nS, 1); if (p < MAXC) idx[p] = i * 4 + 2; }
    if (lv.w == c) { int p = atomicAdd(&nS, 1); if (p < MAXC) idx[p] = i * 4 + 3; }
  }
  __syncthreads();
  const int n = nS < MAXC ? nS : MAXC;

  // load class rows into LDS (fp32, coalesced 1KB per row)
  for (int j = w; j < n; j += 4)
    feat[j][lane] = reinterpret_cast<const float4*>(f + (size_t)idx[j] * D_K)[lane];

  // merge the NSPLIT partials per row (lanes 0..7 hold one split each)
  for (int j = w; j < n; j += 4) {
    float m2 = -1e30f, Ea = 0.f;
    if (lane < NSPLIT) {
      float2 p = part[lane * B_N + idx[j]];
      m2 = p.x; Ea = p.y;
    }
#pragma unroll
    for (int st = 1; st < NSPLIT; st <<= 1) {
      float om = __shfl_xor(m2, st);
      float oa = __shfl_xor(Ea, st);
      float nm = fmaxf(m2, om);
      Ea = Ea * fexp2(m2 - nm) + oa * fexp2(om - nm);
      m2 = nm;
    }
    if (lane == 0) { m2a[j] = m2; Eaa[j] = Ea; Epa[j] = 0.f; sda[j] = 0.f; }
  }
  __syncthreads();

  // Gram tiles: 8x8 pairs per wave-tile, one pair per lane
  const int ntile = (n + 7) >> 3;
  const int jj = lane >> 3, kk = lane & 7;
  for (int tile = w; tile < ntile * ntile; tile += 4) {
    const int j = (tile / ntile) * 8 + jj;
    const int k = (tile % ntile) * 8 + kk;
    const bool ok = (j < n) && (k < n) && (j != k);
    const int jc = j < n ? j : 0, kc = k < n ? k : 0;
    f32x4 acc = {0.f, 0.f, 0.f, 0.f};
#pragma unroll 8
    for (int d = 0; d < 64; ++d) {
      const float4 a = feat[jc][d];
      const float4 b = feat[kc][d];
      acc[0] = fmaf(a.x, b.x, acc[0]);
      acc[1] = fmaf(a.y, b.y, acc[1]);
      acc[2] = fmaf(a.z, b.z, acc[2]);
      acc[3] = fmaf(a.w, b.w, acc[3]);
    }
    float dot = ok ? ((acc[0] + acc[1]) + (acc[2] + acc[3])) : 0.f;
    float ex = ok ? fexp2(fmaf(dot, SCALE2, -m2a[jc])) : 0.f;
#pragma unroll
    for (int st = 1; st < 8; st <<= 1) {
      dot += __shfl_xor(dot, st);
      ex += __shfl_xor(ex, st);
    }
    if (kk == 0 && j < n) {
      atomicAdd(&sda[j], dot);
      atomicAdd(&Epa[j], ex);
    }
  }
  __syncthreads();

  // finalize rows of this class, reduce, one atomic per block
  if (w == 0) {
    float contrib = 0.f;
    if (lane < n) {
      const int j = lane;
      float m2 = m2a[j], Ea = Eaa[j], Ep = Epa[j], sumdot = sda[j];
      float En = fmaxf(Ea - Ep, 0.f);         // self term underflows (exp2(-5000))
      int cntp = n - 1;
      float cntn = (float)(B_N - 1 - cntp);
      float denom = Ep + En / (cntn + 1e-8f);
      float Sadc = -sumdot * INV_T;           // exact fp32 sum of positive logits
      float num = Sadc - (float)cntp * (m2 * LN2) - (float)cntp * logf(denom);
      float dv = (cntp <= 0) ? 1.f : (float)cntp;
      contrib = num / dv;
    }
#pragma unroll
    for (int st = 1; st < 64; st <<= 1) contrib += __shfl_xor(contrib, st);
    if (lane == 0) atomicAdd(out, contrib * (1.f / (float)B_N));
  }
}

extern "C" void kernel_launch(void* const* d_in, const int* in_sizes, int n_in,
                              void* d_out, int out_size, void* d_ws, size_t ws_size,
                              hipStream_t stream) {
  const float* f = (const float*)d_in[0];
  const int* lab = (const int*)d_in[1];

  char* ws = (char*)d_ws;
  u16* fbf = (u16*)ws;                        // 4 MB
  float2* part = (float2*)(ws + 4194304);     // 8*8192*8 = 512 KB

  k_prep<<<2048, 256, 0, stream>>>(f, fbf, (float*)d_out);
  k_main<<<64 * NSPLIT, 256, 0, stream>>>(fbf, part);
  k_final<<<NCLS, 256, 0, stream>>>(f, lab, part, (float*)d_out);
}